// Round 8
// baseline (519.852 us; speedup 1.0000x reference)
//
#include <hip/hip_runtime.h>
#include <hip/hip_fp16.h>

#define N_NODES 200000
#define N_EDGES 6400000
#define D_IN    128
#define D_HID   16
#define D_OUT   172

#define NS1     800       // stage-1 blocks
#define EPB     8000      // edges per stage-1 block: 800*8000 = 6.4M exactly
#define SBN     782       // superbuckets of 256 nodes: 782*256 = 200192 >= 200001
#define SB_NODES 256

// workspace offsets in 4-byte words (peak 13,202,176 words = 52.8 MB)
#define O_BTOT  0          // u32[782]
#define O_BASE  1024       // u32[783]
#define O_SMAX  2048       // u32[2] dynamic-quant max (layer1 / layer2)
#define O_CNT1  2112       // u32[800*782] stage-1 counts (dead after k_scatter1)
#define O_COL   2112       // int[6.4M] CSR col ids (k_csr writes; aliases CNT1)
#define O_ROW   6402112    // int[200001]
#define O_DINV  6602176    // f32[200000]
#define O_PACK  6802176    // u32[6.4M] SB-sorted packed edges (dead after k_csr)
#define O_F16A  6802176    // f16[3.2M] lin1' (aliases PACK)
#define O_Q8A   8402176    // i8[3.2M]
#define O_F16B  9202176    // f16[3.2M] h'
#define O_Q8B   10802176   // i8[3.2M]
#define O_AGG2  6802176    // f32[3.2M] (aliases F16A/Q8A/F16B - dead by gather<0>)

// ---------------------------------------------------------------------------
__global__ __launch_bounds__(256) void k_hist1(const int* __restrict__ dst,
                                               unsigned* __restrict__ counts) {
    __shared__ unsigned cnt[SBN];
    for (int i = threadIdx.x; i < SBN; i += 256) cnt[i] = 0;
    __syncthreads();
    const int* dp = dst + blockIdx.x * EPB;
    for (int i = threadIdx.x; i < EPB; i += 256)
        atomicAdd(&cnt[dp[i] >> 8], 1u);
    __syncthreads();
    unsigned* out = counts + (size_t)blockIdx.x * SBN;
    for (int i = threadIdx.x; i < SBN; i += 256) out[i] = cnt[i];
}

__global__ __launch_bounds__(256) void k_scan_col(unsigned* __restrict__ counts,
                                                  unsigned* __restrict__ btot) {
    __shared__ unsigned arr[NS1];
    int b = blockIdx.x;
    for (int i = threadIdx.x; i < NS1; i += 256)
        arr[i] = counts[(size_t)i * SBN + b];
    __syncthreads();
    if (threadIdx.x < 64) {
        int l = threadIdx.x;
        int lo = l * 13, hi = min(lo + 13, NS1);   // 13*64 = 832 >= 800
        unsigned sum = 0;
        for (int i = lo; i < hi; ++i) sum += arr[i];
        unsigned incl = sum;
#pragma unroll
        for (int o = 1; o < 64; o <<= 1) {
            unsigned tmp = __shfl_up(incl, o);
            if (l >= o) incl += tmp;
        }
        if (l == 63) btot[b] = incl;
        unsigned run = incl - sum;
        for (int i = lo; i < hi; ++i) { unsigned v = arr[i]; arr[i] = run; run += v; }
    }
    __syncthreads();
    for (int i = threadIdx.x; i < NS1; i += 256)
        counts[(size_t)i * SBN + b] = arr[i];
}

__global__ __launch_bounds__(64) void k_scan_base(const unsigned* __restrict__ btot,
                                                  unsigned* __restrict__ base,
                                                  unsigned* __restrict__ smax) {
    int l = threadIdx.x;
    if (l < 2) smax[l] = 0;                        // zero quant-max slots
    int lo = l * 13, hi = min(lo + 13, SBN);       // 13*64 = 832 >= 782
    unsigned sum = 0;
    for (int i = lo; i < hi; ++i) sum += btot[i];
    unsigned incl = sum;
#pragma unroll
    for (int o = 1; o < 64; o <<= 1) {
        unsigned tmp = __shfl_up(incl, o);
        if (l >= o) incl += tmp;
    }
    unsigned run = incl - sum;
    for (int i = lo; i < hi; ++i) { unsigned v = btot[i]; base[i] = run; run += v; }
    if (l == 63) base[SBN] = incl;                  // = N_EDGES
}

// block-local LDS counting sort, then contiguous coalesced write-out
__global__ __launch_bounds__(256) void k_scatter1(const int* __restrict__ src,
                                                  const int* __restrict__ dst,
                                                  const unsigned* __restrict__ counts,
                                                  const unsigned* __restrict__ base,
                                                  unsigned* __restrict__ packed) {
    __shared__ unsigned       sdat[EPB];   // 32.0 KB sorted payloads
    __shared__ unsigned short sbkt[EPB];   // 16.0 KB bucket id per slot
    __shared__ unsigned cnt[SBN];
    __shared__ unsigned off[SBN];
    __shared__ unsigned gbs[SBN];
    __shared__ unsigned wsum[4];
    int t = threadIdx.x;
    const unsigned* crow = counts + (size_t)blockIdx.x * SBN;
    for (int i = t; i < SBN; i += 256) { cnt[i] = 0; gbs[i] = base[i] + crow[i]; }
    __syncthreads();
    const int* sp = src + blockIdx.x * EPB;
    const int* dp = dst + blockIdx.x * EPB;
    // pass 1: histogram
    for (int i = t; i < EPB; i += 256) atomicAdd(&cnt[dp[i] >> 8], 1u);
    __syncthreads();
    // exclusive scan cnt -> off (thread owns 4 bins)
    int lane = t & 63, wid = t >> 6;
    int b0 = t * 4;
    unsigned c0v = (b0 + 0 < SBN) ? cnt[b0 + 0] : 0;
    unsigned c1v = (b0 + 1 < SBN) ? cnt[b0 + 1] : 0;
    unsigned c2v = (b0 + 2 < SBN) ? cnt[b0 + 2] : 0;
    unsigned c3v = (b0 + 3 < SBN) ? cnt[b0 + 3] : 0;
    unsigned mysum = c0v + c1v + c2v + c3v;
    unsigned incl = mysum;
#pragma unroll
    for (int o = 1; o < 64; o <<= 1) {
        unsigned tmp = __shfl_up(incl, o);
        if (lane >= o) incl += tmp;
    }
    if (lane == 63) wsum[wid] = incl;
    __syncthreads();
    unsigned wbase = 0;
    for (int w = 0; w < wid; ++w) wbase += wsum[w];
    unsigned run = wbase + incl - mysum;
    if (b0 + 0 < SBN) { off[b0 + 0] = run; run += c0v; }
    if (b0 + 1 < SBN) { off[b0 + 1] = run; run += c1v; }
    if (b0 + 2 < SBN) { off[b0 + 2] = run; run += c2v; }
    if (b0 + 3 < SBN) { off[b0 + 3] = run; run += c3v; }
    __syncthreads();
    // pass 2: LDS scatter (off becomes running cursor; re-read edges, L2-hot)
    for (int i = t; i < EPB; i += 256) {
        int s = sp[i], d = dp[i];
        unsigned b = (unsigned)d >> 8;
        unsigned slot = atomicAdd(&off[b], 1u);
        sdat[slot] = ((unsigned)(d & (SB_NODES - 1)) << 18) | (unsigned)s;
        sbkt[slot] = (unsigned short)b;
    }
    __syncthreads();
    // write out: consecutive slots of a bucket -> consecutive global addrs
    for (int i = t; i < EPB; i += 256) {
        unsigned b = sbkt[i];
        unsigned start = off[b] - cnt[b];          // off now = end cursor
        packed[gbs[b] + (i - start)] = sdat[i];
    }
}

// one 256-thread block per 256-node SB -> rowptr, col, dinv
__global__ __launch_bounds__(256) void k_csr(const unsigned* __restrict__ packed,
                                             const unsigned* __restrict__ base,
                                             int* __restrict__ rowptr,
                                             float* __restrict__ dinv,
                                             int* __restrict__ col) {
    __shared__ unsigned cnt[SB_NODES];
    __shared__ unsigned off[SB_NODES];
    __shared__ unsigned wsum[4];
    int t = threadIdx.x, sb = blockIdx.x;
    unsigned beg = base[sb], end = base[sb + 1];
    cnt[t] = 0;
    __syncthreads();
    for (unsigned i = beg + t; i < end; i += 256)
        atomicAdd(&cnt[packed[i] >> 18], 1u);
    __syncthreads();
    unsigned e = cnt[t];
    int lane = t & 63, wid = t >> 6;
    unsigned incl = e;
#pragma unroll
    for (int o = 1; o < 64; o <<= 1) {
        unsigned tmp = __shfl_up(incl, o);
        if (lane >= o) incl += tmp;
    }
    if (lane == 63) wsum[wid] = incl;
    __syncthreads();
    unsigned wbase = 0;
    for (int w = 0; w < wid; ++w) wbase += wsum[w];
    unsigned ex = wbase + incl - e;
    off[t] = ex;
    int n0 = sb * SB_NODES + t;
    if (n0 <= N_NODES) rowptr[n0] = (int)(beg + ex);
    if (n0 <  N_NODES) dinv[n0]   = rsqrtf((float)(e + 1));
    __syncthreads();
    for (unsigned i = beg + t; i < end; i += 256) {
        unsigned p = packed[i];
        unsigned slot = atomicAdd(&off[p >> 18], 1u);
        col[beg + slot] = (int)(p & 0x3FFFFu);
    }
}

// ---------------------------------------------------------------------------
// lin' = (x @ W1) * dinv[n] -> fp16; track global max|v| for int8 scale
__global__ __launch_bounds__(256) void k_lin1(const float* __restrict__ x,
                                              const float* __restrict__ W1,
                                              const float* __restrict__ dinv,
                                              __half* __restrict__ lin,
                                              unsigned* __restrict__ smax0) {
    __shared__ float sW[D_IN * D_HID];
    __shared__ unsigned lmax;
    if (threadIdx.x == 0) lmax = 0;
    for (int t = threadIdx.x; t < D_IN * D_HID; t += 256) sW[t] = W1[t];
    __syncthreads();

    int g  = threadIdx.x & 3;
    int nl = threadIdx.x >> 2;
    int n  = blockIdx.x * 64 + nl;

    float acc[16];
#pragma unroll
    for (int j = 0; j < 16; ++j) acc[j] = 0.f;

    const float4* xr = (const float4*)(x + (size_t)n * D_IN + g * 32);
#pragma unroll
    for (int i = 0; i < 8; ++i) {
        float4 xv = xr[i];
        int k = g * 32 + i * 4;
#pragma unroll
        for (int j = 0; j < 16; ++j) {
            acc[j] += xv.x * sW[(k + 0) * 16 + j] + xv.y * sW[(k + 1) * 16 + j]
                    + xv.z * sW[(k + 2) * 16 + j] + xv.w * sW[(k + 3) * 16 + j];
        }
    }
#pragma unroll
    for (int j = 0; j < 16; ++j) {
        acc[j] += __shfl_xor(acc[j], 1);
        acc[j] += __shfl_xor(acc[j], 2);
    }
    float di = dinv[n];
    float v0 = acc[g * 4 + 0] * di, v1 = acc[g * 4 + 1] * di;
    float v2 = acc[g * 4 + 2] * di, v3 = acc[g * 4 + 3] * di;
    ushort4 pk;
    pk.x = __half_as_ushort(__float2half(v0));
    pk.y = __half_as_ushort(__float2half(v1));
    pk.z = __half_as_ushort(__float2half(v2));
    pk.w = __half_as_ushort(__float2half(v3));
    *(ushort4*)(lin + (size_t)n * 16 + g * 4) = pk;
    float m = fmaxf(fmaxf(fabsf(v0), fabsf(v1)), fmaxf(fabsf(v2), fabsf(v3)));
    atomicMax(&lmax, __float_as_uint(m));
    __syncthreads();
    if (threadIdx.x == 0) atomicMax(smax0, lmax);
}

// fp16 -> int8 symmetric quant, scale = max/127. Thread per 4 values.
__global__ __launch_bounds__(256) void k_quant(const __half2* __restrict__ hin,
                                               const unsigned* __restrict__ smax,
                                               uchar4* __restrict__ q8) {
    int i = blockIdx.x * 256 + threadIdx.x;   // grid 3125 -> 800000 exact
    float mx = __uint_as_float(*smax);
    float rs = mx > 0.f ? 127.0f / mx : 0.f;
    __half2 p0 = hin[2 * i], p1 = hin[2 * i + 1];
    float2 f0 = __half22float2(p0), f1 = __half22float2(p1);
    int q0 = min(max(__float2int_rn(f0.x * rs), -127), 127);
    int q1 = min(max(__float2int_rn(f0.y * rs), -127), 127);
    int q2 = min(max(__float2int_rn(f1.x * rs), -127), 127);
    int q3 = min(max(__float2int_rn(f1.y * rs), -127), 127);
    uchar4 o;
    o.x = (unsigned char)q0; o.y = (unsigned char)q1;
    o.z = (unsigned char)q2; o.w = (unsigned char)q3;
    q8[i] = o;
}

// ---------------------------------------------------------------------------
// int8 pull-gather, R5/R7 structure: 16 lanes/node, 8 loads in flight/lane,
// exact int32 accumulation, one dequant at the end. Table = 3.2 MB (L2-fit).
// MODE 1: v = relu(acc*sc + b1)*dd -> fp16 + track max.  MODE 0: fp32 out.
template <int MODE>
__global__ __launch_bounds__(256) void k_gather8(const int* __restrict__ rowptr,
                                                 const int* __restrict__ col,
                                                 const float* __restrict__ dinv,
                                                 const signed char* __restrict__ q8,
                                                 const unsigned* __restrict__ sin,
                                                 unsigned* __restrict__ sout,
                                                 const float* __restrict__ bias,
                                                 void* __restrict__ outv) {
    __shared__ unsigned lmax;
    int t = threadIdx.x;
    if (MODE) {
        if (t == 0) lmax = 0;
        __syncthreads();
    }
    int n = blockIdx.x * 16 + (t >> 4);   // grid exact: 12500*16
    int lane = t & 15;
    int beg = rowptr[n], end = rowptr[n + 1];
    int a0 = q8[n * 16 + lane];           // self loop (pre-scaled source)
    int a1 = 0, a2 = 0, a3 = 0, a4 = 0, a5 = 0, a6 = 0, a7 = 0;
    int i = beg;
    for (; i + 8 <= end; i += 8) {
        int s0 = col[i + 0], s1 = col[i + 1], s2 = col[i + 2], s3 = col[i + 3];
        int s4 = col[i + 4], s5 = col[i + 5], s6 = col[i + 6], s7 = col[i + 7];
        int b0 = q8[s0 * 16 + lane], b1v = q8[s1 * 16 + lane];
        int b2 = q8[s2 * 16 + lane], b3 = q8[s3 * 16 + lane];
        int b4 = q8[s4 * 16 + lane], b5 = q8[s5 * 16 + lane];
        int b6 = q8[s6 * 16 + lane], b7 = q8[s7 * 16 + lane];
        a0 += b0; a1 += b1v; a2 += b2; a3 += b3;
        a4 += b4; a5 += b5; a6 += b6; a7 += b7;
    }
    for (; i < end; ++i) a0 += q8[col[i] * 16 + lane];
    int isum = ((a0 + a1) + (a2 + a3)) + ((a4 + a5) + (a6 + a7));
    float dd = dinv[n];
    float v = (float)isum * (__uint_as_float(*sin) * (1.0f / 127.0f)) * dd;
    if (MODE) {
        v = fmaxf(v + bias[lane], 0.f) * dd;
        ((__half*)outv)[n * 16 + lane] = __float2half(v);
        atomicMax(&lmax, __float_as_uint(v));
        __syncthreads();
        if (t == 0) atomicMax(sout, lmax);
    } else {
        ((float*)outv)[n * 16 + lane] = v;
    }
}

// ---------------------------------------------------------------------------
// logits = agg2 @ W2 + b2; log_softmax. 64 nodes/block, 4 threads/node.
__global__ __launch_bounds__(256) void k_out(const float* __restrict__ agg2,
                                             const float* __restrict__ W2,
                                             const float* __restrict__ b2,
                                             float* __restrict__ out) {
    __shared__ float sWt[D_OUT * D_HID];   // transposed [c][k]
    __shared__ float sb[D_OUT];
    __shared__ float sl[64 * D_OUT];       // logits, 44 KB
    __shared__ float sls[64];
    int t = threadIdx.x;
    for (int m = t; m < D_OUT * D_HID; m += 256)
        sWt[m] = W2[(m & 15) * D_OUT + (m >> 4)];
    for (int m = t; m < D_OUT; m += 256) sb[m] = b2[m];
    __syncthreads();

    int nl = t >> 2, q = t & 3;
    int n  = blockIdx.x * 64 + nl;         // grid exact: 3125*64
    const float4* ar = (const float4*)(agg2 + (size_t)n * 16);
    float4 a0 = ar[0], a1 = ar[1], a2 = ar[2], a3 = ar[3];
    float a[16] = {a0.x, a0.y, a0.z, a0.w, a1.x, a1.y, a1.z, a1.w,
                   a2.x, a2.y, a2.z, a2.w, a3.x, a3.y, a3.z, a3.w};

    float mloc = -INFINITY;
    float* srow = sl + nl * D_OUT;
#pragma unroll 4
    for (int i = 0; i < 43; ++i) {
        int c = q + 4 * i;
        const float4* wr = (const float4*)(sWt + c * 16);
        float4 w0 = wr[0], w1 = wr[1], w2 = wr[2], w3 = wr[3];
        float l = sb[c];
        l += a[0]  * w0.x + a[1]  * w0.y + a[2]  * w0.z + a[3]  * w0.w;
        l += a[4]  * w1.x + a[5]  * w1.y + a[6]  * w1.z + a[7]  * w1.w;
        l += a[8]  * w2.x + a[9]  * w2.y + a[10] * w2.z + a[11] * w2.w;
        l += a[12] * w3.x + a[13] * w3.y + a[14] * w3.z + a[15] * w3.w;
        srow[c] = l;
        mloc = fmaxf(mloc, l);
    }
    mloc = fmaxf(mloc, __shfl_xor(mloc, 1));
    mloc = fmaxf(mloc, __shfl_xor(mloc, 2));
    float sloc = 0.f;
#pragma unroll 4
    for (int i = 0; i < 43; ++i) sloc += __expf(srow[q + 4 * i] - mloc);
    sloc += __shfl_xor(sloc, 1);
    sloc += __shfl_xor(sloc, 2);
    if (q == 0) sls[nl] = mloc + __logf(sloc);
    __syncthreads();

    const float4* sl4 = (const float4*)sl;
    float4* ob = (float4*)(out + (size_t)blockIdx.x * 64 * D_OUT);
    for (int jj = t; jj < 64 * D_OUT / 4; jj += 256) {
        float4 v = sl4[jj];
        float ls = sls[jj / 43];
        v.x -= ls; v.y -= ls; v.z -= ls; v.w -= ls;
        ob[jj] = v;
    }
}

// ---------------------------------------------------------------------------
extern "C" void kernel_launch(void* const* d_in, const int* in_sizes, int n_in,
                              void* d_out, int out_size, void* d_ws, size_t ws_size,
                              hipStream_t stream) {
    const float* x     = (const float*)d_in[0];
    const int*   edges = (const int*)d_in[1];
    const float* W1    = (const float*)d_in[2];
    const float* b1    = (const float*)d_in[3];
    const float* W2    = (const float*)d_in[4];
    const float* b2    = (const float*)d_in[5];
    float*       out   = (float*)d_out;

    const int* src = edges;
    const int* dst = edges + N_EDGES;

    unsigned* ws     = (unsigned*)d_ws;
    unsigned* btot   = ws + O_BTOT;
    unsigned* base   = ws + O_BASE;
    unsigned* smax   = ws + O_SMAX;
    unsigned* counts = ws + O_CNT1;
    int*      col    = (int*)(ws + O_COL);      // aliases counts (dead by k_csr)
    int*      rowptr = (int*)(ws + O_ROW);
    float*    dinv   = (float*)(ws + O_DINV);
    unsigned* packed = ws + O_PACK;             // dead after k_csr
    __half*   f16a   = (__half*)(ws + O_F16A);  // aliases packed
    signed char* q8a = (signed char*)(ws + O_Q8A);
    __half*   f16b   = (__half*)(ws + O_F16B);
    signed char* q8b = (signed char*)(ws + O_Q8B);
    float*    agg2   = (float*)(ws + O_AGG2);   // aliases f16a/q8a/f16b (dead)

    // --- CSR build: zero global atomics ---
    k_hist1    <<<NS1, 256, 0, stream>>>(dst, counts);
    k_scan_col <<<SBN, 256, 0, stream>>>(counts, btot);
    k_scan_base<<<1,    64, 0, stream>>>(btot, base, smax);
    k_scatter1 <<<NS1, 256, 0, stream>>>(src, dst, counts, base, packed);
    k_csr      <<<SBN, 256, 0, stream>>>(packed, base, rowptr, dinv, col);

    // --- layer 1: project + prescale (fp16 + max), quantize, int8 gather ---
    k_lin1     <<<N_NODES / 64, 256, 0, stream>>>(x, W1, dinv, f16a, smax);
    k_quant    <<<3125, 256, 0, stream>>>((const __half2*)f16a, smax, (uchar4*)q8a);
    k_gather8<1><<<N_NODES / 16, 256, 0, stream>>>(rowptr, col, dinv, q8a,
                                                   smax, smax + 1, b1, f16b);
    // --- layer 2: quantize h', int8 gather, then 16->172 + log_softmax ---
    k_quant    <<<3125, 256, 0, stream>>>((const __half2*)f16b, smax + 1, (uchar4*)q8b);
    k_gather8<0><<<N_NODES / 16, 256, 0, stream>>>(rowptr, col, dinv, q8b,
                                                   smax + 1, nullptr, b1, agg2);
    k_out      <<<N_NODES / 64, 256, 0, stream>>>(agg2, W2, b2, out);
}

// Round 9
// 425.853 us; speedup vs baseline: 1.2207x; 1.2207x over previous
//
#include <hip/hip_runtime.h>
#include <hip/hip_fp16.h>

#define N_NODES 200000
#define N_EDGES 6400000
#define D_IN    128
#define D_HID   16
#define D_OUT   172

#define NS1     800       // stage-1 blocks
#define EPB     8000      // edges per stage-1 block: 800*8000 = 6.4M exactly
#define SBN     782       // superbuckets of 256 nodes: 782*256 = 200192 >= 200001
#define SB_NODES 256

// workspace offsets in 4-byte words (peak 13,202,112 words = 52.8 MB)
#define O_BTOT  0          // u32[782]
#define O_BASE  1024       // u32[783]
#define O_CNT1  2048       // u32[800*782] stage-1 counts (dead after k_scatter1)
#define O_COL   2048       // int[6.4M] CSR col ids (k_csr writes; aliases CNT1)
#define O_ROW   6402048    // int[200001]
#define O_DINV  6602112    // f32[200000]
#define O_PACK  6802112    // u32[6.4M] SB-sorted packed edges (dead after k_csr)
#define O_F16A  6802112    // f16[3.2M] lin1' (aliases PACK)
#define O_F16B  8402112    // f16[3.2M] h'
#define O_AGG2  10002112   // f32[3.2M]

// ---------------------------------------------------------------------------
__global__ __launch_bounds__(256) void k_hist1(const int* __restrict__ dst,
                                               unsigned* __restrict__ counts) {
    __shared__ unsigned cnt[SBN];
    for (int i = threadIdx.x; i < SBN; i += 256) cnt[i] = 0;
    __syncthreads();
    const int* dp = dst + blockIdx.x * EPB;
    for (int i = threadIdx.x; i < EPB; i += 256)
        atomicAdd(&cnt[dp[i] >> 8], 1u);
    __syncthreads();
    unsigned* out = counts + (size_t)blockIdx.x * SBN;
    for (int i = threadIdx.x; i < SBN; i += 256) out[i] = cnt[i];
}

__global__ __launch_bounds__(256) void k_scan_col(unsigned* __restrict__ counts,
                                                  unsigned* __restrict__ btot) {
    __shared__ unsigned arr[NS1];
    int b = blockIdx.x;
    for (int i = threadIdx.x; i < NS1; i += 256)
        arr[i] = counts[(size_t)i * SBN + b];
    __syncthreads();
    if (threadIdx.x < 64) {
        int l = threadIdx.x;
        int lo = l * 13, hi = min(lo + 13, NS1);   // 13*64 = 832 >= 800
        unsigned sum = 0;
        for (int i = lo; i < hi; ++i) sum += arr[i];
        unsigned incl = sum;
#pragma unroll
        for (int o = 1; o < 64; o <<= 1) {
            unsigned tmp = __shfl_up(incl, o);
            if (l >= o) incl += tmp;
        }
        if (l == 63) btot[b] = incl;
        unsigned run = incl - sum;
        for (int i = lo; i < hi; ++i) { unsigned v = arr[i]; arr[i] = run; run += v; }
    }
    __syncthreads();
    for (int i = threadIdx.x; i < NS1; i += 256)
        counts[(size_t)i * SBN + b] = arr[i];
}

__global__ __launch_bounds__(64) void k_scan_base(const unsigned* __restrict__ btot,
                                                  unsigned* __restrict__ base) {
    int l = threadIdx.x;
    int lo = l * 13, hi = min(lo + 13, SBN);       // 13*64 = 832 >= 782
    unsigned sum = 0;
    for (int i = lo; i < hi; ++i) sum += btot[i];
    unsigned incl = sum;
#pragma unroll
    for (int o = 1; o < 64; o <<= 1) {
        unsigned tmp = __shfl_up(incl, o);
        if (l >= o) incl += tmp;
    }
    unsigned run = incl - sum;
    for (int i = lo; i < hi; ++i) { unsigned v = btot[i]; base[i] = run; run += v; }
    if (l == 63) base[SBN] = incl;                  // = N_EDGES
}

// block-local LDS counting sort, then contiguous coalesced write-out
__global__ __launch_bounds__(256) void k_scatter1(const int* __restrict__ src,
                                                  const int* __restrict__ dst,
                                                  const unsigned* __restrict__ counts,
                                                  const unsigned* __restrict__ base,
                                                  unsigned* __restrict__ packed) {
    __shared__ unsigned       sdat[EPB];   // 32.0 KB sorted payloads
    __shared__ unsigned short sbkt[EPB];   // 16.0 KB bucket id per slot
    __shared__ unsigned cnt[SBN];
    __shared__ unsigned off[SBN];
    __shared__ unsigned gbs[SBN];
    __shared__ unsigned wsum[4];
    int t = threadIdx.x;
    const unsigned* crow = counts + (size_t)blockIdx.x * SBN;
    for (int i = t; i < SBN; i += 256) { cnt[i] = 0; gbs[i] = base[i] + crow[i]; }
    __syncthreads();
    const int* sp = src + blockIdx.x * EPB;
    const int* dp = dst + blockIdx.x * EPB;
    for (int i = t; i < EPB; i += 256) atomicAdd(&cnt[dp[i] >> 8], 1u);
    __syncthreads();
    int lane = t & 63, wid = t >> 6;
    int b0 = t * 4;
    unsigned c0v = (b0 + 0 < SBN) ? cnt[b0 + 0] : 0;
    unsigned c1v = (b0 + 1 < SBN) ? cnt[b0 + 1] : 0;
    unsigned c2v = (b0 + 2 < SBN) ? cnt[b0 + 2] : 0;
    unsigned c3v = (b0 + 3 < SBN) ? cnt[b0 + 3] : 0;
    unsigned mysum = c0v + c1v + c2v + c3v;
    unsigned incl = mysum;
#pragma unroll
    for (int o = 1; o < 64; o <<= 1) {
        unsigned tmp = __shfl_up(incl, o);
        if (lane >= o) incl += tmp;
    }
    if (lane == 63) wsum[wid] = incl;
    __syncthreads();
    unsigned wbase = 0;
    for (int w = 0; w < wid; ++w) wbase += wsum[w];
    unsigned run = wbase + incl - mysum;
    if (b0 + 0 < SBN) { off[b0 + 0] = run; run += c0v; }
    if (b0 + 1 < SBN) { off[b0 + 1] = run; run += c1v; }
    if (b0 + 2 < SBN) { off[b0 + 2] = run; run += c2v; }
    if (b0 + 3 < SBN) { off[b0 + 3] = run; run += c3v; }
    __syncthreads();
    for (int i = t; i < EPB; i += 256) {
        int s = sp[i], d = dp[i];
        unsigned b = (unsigned)d >> 8;
        unsigned slot = atomicAdd(&off[b], 1u);
        sdat[slot] = ((unsigned)(d & (SB_NODES - 1)) << 18) | (unsigned)s;
        sbkt[slot] = (unsigned short)b;
    }
    __syncthreads();
    for (int i = t; i < EPB; i += 256) {
        unsigned b = sbkt[i];
        unsigned start = off[b] - cnt[b];          // off now = end cursor
        packed[gbs[b] + (i - start)] = sdat[i];
    }
}

// one 256-thread block per 256-node SB -> rowptr, col, dinv
__global__ __launch_bounds__(256) void k_csr(const unsigned* __restrict__ packed,
                                             const unsigned* __restrict__ base,
                                             int* __restrict__ rowptr,
                                             float* __restrict__ dinv,
                                             int* __restrict__ col) {
    __shared__ unsigned cnt[SB_NODES];
    __shared__ unsigned off[SB_NODES];
    __shared__ unsigned wsum[4];
    int t = threadIdx.x, sb = blockIdx.x;
    unsigned beg = base[sb], end = base[sb + 1];
    cnt[t] = 0;
    __syncthreads();
    for (unsigned i = beg + t; i < end; i += 256)
        atomicAdd(&cnt[packed[i] >> 18], 1u);
    __syncthreads();
    unsigned e = cnt[t];
    int lane = t & 63, wid = t >> 6;
    unsigned incl = e;
#pragma unroll
    for (int o = 1; o < 64; o <<= 1) {
        unsigned tmp = __shfl_up(incl, o);
        if (lane >= o) incl += tmp;
    }
    if (lane == 63) wsum[wid] = incl;
    __syncthreads();
    unsigned wbase = 0;
    for (int w = 0; w < wid; ++w) wbase += wsum[w];
    unsigned ex = wbase + incl - e;
    off[t] = ex;
    int n0 = sb * SB_NODES + t;
    if (n0 <= N_NODES) rowptr[n0] = (int)(beg + ex);
    if (n0 <  N_NODES) dinv[n0]   = rsqrtf((float)(e + 1));
    __syncthreads();
    for (unsigned i = beg + t; i < end; i += 256) {
        unsigned p = packed[i];
        unsigned slot = atomicAdd(&off[p >> 18], 1u);
        col[beg + slot] = (int)(p & 0x3FFFFu);
    }
}

// ---------------------------------------------------------------------------
// lin' = (x @ W1) * dinv[n], stored fp16
__global__ __launch_bounds__(256) void k_lin1(const float* __restrict__ x,
                                              const float* __restrict__ W1,
                                              const float* __restrict__ dinv,
                                              __half* __restrict__ lin) {
    __shared__ float sW[D_IN * D_HID];
    for (int t = threadIdx.x; t < D_IN * D_HID; t += 256) sW[t] = W1[t];
    __syncthreads();

    int g  = threadIdx.x & 3;
    int nl = threadIdx.x >> 2;
    int n  = blockIdx.x * 64 + nl;   // grid exact: 3125*64

    float acc[16];
#pragma unroll
    for (int j = 0; j < 16; ++j) acc[j] = 0.f;

    const float4* xr = (const float4*)(x + (size_t)n * D_IN + g * 32);
#pragma unroll
    for (int i = 0; i < 8; ++i) {
        float4 xv = xr[i];
        int k = g * 32 + i * 4;
#pragma unroll
        for (int j = 0; j < 16; ++j) {
            acc[j] += xv.x * sW[(k + 0) * 16 + j] + xv.y * sW[(k + 1) * 16 + j]
                    + xv.z * sW[(k + 2) * 16 + j] + xv.w * sW[(k + 3) * 16 + j];
        }
    }
#pragma unroll
    for (int j = 0; j < 16; ++j) {
        acc[j] += __shfl_xor(acc[j], 1);
        acc[j] += __shfl_xor(acc[j], 2);
    }
    float di = dinv[n];
    ushort4 pk;
    pk.x = __half_as_ushort(__float2half(acc[g * 4 + 0] * di));
    pk.y = __half_as_ushort(__float2half(acc[g * 4 + 1] * di));
    pk.z = __half_as_ushort(__float2half(acc[g * 4 + 2] * di));
    pk.w = __half_as_ushort(__float2half(acc[g * 4 + 3] * di));
    *(ushort4*)(lin + (size_t)n * 16 + g * 4) = pk;
}

// ---------------------------------------------------------------------------
// pull-gather, weight-folded, half2 per lane: 8 lanes/node, 8 nodes/wave,
// 8 edges in flight per lane -> 64 outstanding 32B requests per wave.
// MODE 1: v = relu(acc*dd + b1)*dd -> fp16 out.  MODE 0: v = acc*dd -> fp32 out.
template <int MODE>
__global__ __launch_bounds__(256) void k_gather(const int* __restrict__ rowptr,
                                                const int* __restrict__ col,
                                                const float* __restrict__ dinv,
                                                const __half2* __restrict__ fin,
                                                const float* __restrict__ bias,
                                                void* __restrict__ outv) {
    int t = threadIdx.x;
    int n = blockIdx.x * 32 + (t >> 3);   // 32 nodes/block, grid exact: 6250*32
    int lane = t & 7;                     // owns features 2*lane, 2*lane+1
    int beg = rowptr[n], end = rowptr[n + 1];
    float2 a0 = __half22float2(fin[n * 8 + lane]);   // self loop (pre-scaled)
    float2 a1 = {0,0}, a2 = {0,0}, a3 = {0,0};
    float2 a4 = {0,0}, a5 = {0,0}, a6 = {0,0}, a7 = {0,0};
    int i = beg;
    for (; i + 8 <= end; i += 8) {
        int s0 = col[i + 0], s1 = col[i + 1], s2 = col[i + 2], s3 = col[i + 3];
        int s4 = col[i + 4], s5 = col[i + 5], s6 = col[i + 6], s7 = col[i + 7];
        __half2 h0 = fin[s0 * 8 + lane], h1 = fin[s1 * 8 + lane];
        __half2 h2 = fin[s2 * 8 + lane], h3 = fin[s3 * 8 + lane];
        __half2 h4 = fin[s4 * 8 + lane], h5 = fin[s5 * 8 + lane];
        __half2 h6 = fin[s6 * 8 + lane], h7 = fin[s7 * 8 + lane];
        float2 f0 = __half22float2(h0), f1 = __half22float2(h1);
        float2 f2 = __half22float2(h2), f3 = __half22float2(h3);
        float2 f4 = __half22float2(h4), f5 = __half22float2(h5);
        float2 f6 = __half22float2(h6), f7 = __half22float2(h7);
        a0.x += f0.x; a0.y += f0.y;  a1.x += f1.x; a1.y += f1.y;
        a2.x += f2.x; a2.y += f2.y;  a3.x += f3.x; a3.y += f3.y;
        a4.x += f4.x; a4.y += f4.y;  a5.x += f5.x; a5.y += f5.y;
        a6.x += f6.x; a6.y += f6.y;  a7.x += f7.x; a7.y += f7.y;
    }
    for (; i < end; ++i) {
        float2 f = __half22float2(fin[col[i] * 8 + lane]);
        a0.x += f.x; a0.y += f.y;
    }
    float vx = ((a0.x + a1.x) + (a2.x + a3.x)) + ((a4.x + a5.x) + (a6.x + a7.x));
    float vy = ((a0.y + a1.y) + (a2.y + a3.y)) + ((a4.y + a5.y) + (a6.y + a7.y));
    float dd = dinv[n];
    vx *= dd; vy *= dd;
    if (MODE) {
        float2 b2v = ((const float2*)bias)[lane];
        vx = fmaxf(vx + b2v.x, 0.f) * dd;
        vy = fmaxf(vy + b2v.y, 0.f) * dd;
        ((__half2*)outv)[n * 8 + lane] = __floats2half2_rn(vx, vy);
    } else {
        ((float2*)outv)[n * 8 + lane] = make_float2(vx, vy);
    }
}

// ---------------------------------------------------------------------------
// logits = agg2 @ W2 + b2; log_softmax. 64 nodes/block, 4 threads/node.
__global__ __launch_bounds__(256) void k_out(const float* __restrict__ agg2,
                                             const float* __restrict__ W2,
                                             const float* __restrict__ b2,
                                             float* __restrict__ out) {
    __shared__ float sWt[D_OUT * D_HID];   // transposed [c][k]
    __shared__ float sb[D_OUT];
    __shared__ float sl[64 * D_OUT];       // logits, 44 KB
    __shared__ float sls[64];
    int t = threadIdx.x;
    for (int m = t; m < D_OUT * D_HID; m += 256)
        sWt[m] = W2[(m & 15) * D_OUT + (m >> 4)];
    for (int m = t; m < D_OUT; m += 256) sb[m] = b2[m];
    __syncthreads();

    int nl = t >> 2, q = t & 3;
    int n  = blockIdx.x * 64 + nl;         // grid exact: 3125*64
    const float4* ar = (const float4*)(agg2 + (size_t)n * 16);
    float4 a0 = ar[0], a1 = ar[1], a2 = ar[2], a3 = ar[3];
    float a[16] = {a0.x, a0.y, a0.z, a0.w, a1.x, a1.y, a1.z, a1.w,
                   a2.x, a2.y, a2.z, a2.w, a3.x, a3.y, a3.z, a3.w};

    float mloc = -INFINITY;
    float* srow = sl + nl * D_OUT;
#pragma unroll 4
    for (int i = 0; i < 43; ++i) {
        int c = q + 4 * i;
        const float4* wr = (const float4*)(sWt + c * 16);
        float4 w0 = wr[0], w1 = wr[1], w2 = wr[2], w3 = wr[3];
        float l = sb[c];
        l += a[0]  * w0.x + a[1]  * w0.y + a[2]  * w0.z + a[3]  * w0.w;
        l += a[4]  * w1.x + a[5]  * w1.y + a[6]  * w1.z + a[7]  * w1.w;
        l += a[8]  * w2.x + a[9]  * w2.y + a[10] * w2.z + a[11] * w2.w;
        l += a[12] * w3.x + a[13] * w3.y + a[14] * w3.z + a[15] * w3.w;
        srow[c] = l;
        mloc = fmaxf(mloc, l);
    }
    mloc = fmaxf(mloc, __shfl_xor(mloc, 1));
    mloc = fmaxf(mloc, __shfl_xor(mloc, 2));
    float sloc = 0.f;
#pragma unroll 4
    for (int i = 0; i < 43; ++i) sloc += __expf(srow[q + 4 * i] - mloc);
    sloc += __shfl_xor(sloc, 1);
    sloc += __shfl_xor(sloc, 2);
    if (q == 0) sls[nl] = mloc + __logf(sloc);
    __syncthreads();

    const float4* sl4 = (const float4*)sl;
    float4* ob = (float4*)(out + (size_t)blockIdx.x * 64 * D_OUT);
    for (int jj = t; jj < 64 * D_OUT / 4; jj += 256) {
        float4 v = sl4[jj];
        float ls = sls[jj / 43];
        v.x -= ls; v.y -= ls; v.z -= ls; v.w -= ls;
        ob[jj] = v;
    }
}

// ---------------------------------------------------------------------------
extern "C" void kernel_launch(void* const* d_in, const int* in_sizes, int n_in,
                              void* d_out, int out_size, void* d_ws, size_t ws_size,
                              hipStream_t stream) {
    const float* x     = (const float*)d_in[0];
    const int*   edges = (const int*)d_in[1];
    const float* W1    = (const float*)d_in[2];
    const float* b1    = (const float*)d_in[3];
    const float* W2    = (const float*)d_in[4];
    const float* b2    = (const float*)d_in[5];
    float*       out   = (float*)d_out;

    const int* src = edges;
    const int* dst = edges + N_EDGES;

    unsigned* ws     = (unsigned*)d_ws;
    unsigned* btot   = ws + O_BTOT;
    unsigned* base   = ws + O_BASE;
    unsigned* counts = ws + O_CNT1;
    int*      col    = (int*)(ws + O_COL);      // aliases counts (dead by k_csr)
    int*      rowptr = (int*)(ws + O_ROW);
    float*    dinv   = (float*)(ws + O_DINV);
    unsigned* packed = ws + O_PACK;             // dead after k_csr
    __half*   f16a   = (__half*)(ws + O_F16A);  // aliases packed
    __half*   f16b   = (__half*)(ws + O_F16B);
    float*    agg2   = (float*)(ws + O_AGG2);

    // --- CSR build: zero global atomics ---
    k_hist1    <<<NS1, 256, 0, stream>>>(dst, counts);
    k_scan_col <<<SBN, 256, 0, stream>>>(counts, btot);
    k_scan_base<<<1,    64, 0, stream>>>(btot, base);
    k_scatter1 <<<NS1, 256, 0, stream>>>(src, dst, counts, base, packed);
    k_csr      <<<SBN, 256, 0, stream>>>(packed, base, rowptr, dinv, col);

    // --- layer 1: project 128->16 (pre-scaled, fp16), gather (relu fused) ---
    k_lin1     <<<N_NODES / 64, 256, 0, stream>>>(x, W1, dinv, f16a);
    k_gather<1><<<N_NODES / 32, 256, 0, stream>>>(rowptr, col, dinv,
                                                  (const __half2*)f16a, b1, f16b);

    // --- layer 2 (reassociated): gather h', then 16->172 + log_softmax ---
    k_gather<0><<<N_NODES / 32, 256, 0, stream>>>(rowptr, col, dinv,
                                                  (const __half2*)f16b, b1, agg2);
    k_out      <<<N_NODES / 64, 256, 0, stream>>>(agg2, W2, b2, out);
}